// Round 7
// baseline (1497.340 us; speedup 1.0000x reference)
//
// EncoderDecoder1DBlock on MI355X (gfx950).
// Int8 fake-quant reproduced EXACTLY via integer-valued bf16 MFMA GEMMs.
// R7: occupancy fix. R6 showed big gemms LATENCY-bound: 256 blocks = 1
// block/CU, 256 B in flight/CU, barrier drain with nothing to overlap.
// Gemm now templated on TM x TN: big gemms use 128x64 tiles (512-2048
// blocks = 2-3/CU) + BK=64 (half the barriers, 2x bytes per stage);
// PV uses 64x64. XCD row-band swizzle kept (FETCH 143->57 MB confirmed).
// Workspace: 161 MB.

#include <hip/hip_runtime.h>
#include <hip/hip_bf16.h>

typedef __hip_bfloat16 bf16;
typedef __attribute__((ext_vector_type(8))) short bf16x8;   // 8 bf16 = 4 VGPRs
typedef __attribute__((ext_vector_type(4))) float floatx4;

#define NBATCH 8
#define SEQ    512
#define DIM    1024
#define NHEAD  16
#define DHEAD  64
#define FF     4096
#define NTOK   (NBATCH*SEQ)            // 4096
#define NROW   (NBATCH*NHEAD*SEQ)      // 65536 attention rows

__device__ inline void atomicMaxF(float* p, float v){ atomicMax((unsigned int*)p, __float_as_uint(v)); } // v >= 0

// async global->LDS, 16 bytes per lane (LDS dest = wave-uniform base + lane*16)
__device__ inline void gld16(bf16* lds, const bf16* g){
  __builtin_amdgcn_global_load_lds(
      (const __attribute__((address_space(1))) void*)g,
      (__attribute__((address_space(3))) void*)lds, 16, 0, 0);
}

// ---- 64-way stripe: sub-slot j lives at stripe[j*16] (64B apart) ----
__device__ inline float stripe_max(const float* __restrict__ st){
  float v = st[(threadIdx.x & 63)*16];
#pragma unroll
  for (int o = 32; o > 0; o >>= 1) v = fmaxf(v, __shfl_xor(v, o));
  return v;
}
__device__ inline float stripe_min(const float* __restrict__ st){
  float v = st[(threadIdx.x & 63)*16];
#pragma unroll
  for (int o = 32; o > 0; o >>= 1) v = fminf(v, __shfl_xor(v, o));
  return v;
}

// blockDim.x == 256 assumed (4 waves). OP: 0=sum, 1=max, 2=min
template<int OP>
__device__ inline float block_reduce256(float v){
  __shared__ float red[4];
#pragma unroll
  for (int o = 32; o > 0; o >>= 1){
    float t = __shfl_down(v, o);
    v = OP==0 ? v + t : (OP==1 ? fmaxf(v, t) : fminf(v, t));
  }
  int lane = threadIdx.x & 63, w = threadIdx.x >> 6;
  if (lane == 0) red[w] = v;
  __syncthreads();
  float r = OP==0 ? (red[0]+red[1])+(red[2]+red[3])
          : OP==1 ? fmaxf(fmaxf(red[0],red[1]), fmaxf(red[2],red[3]))
                  : fminf(fminf(red[0],red[1]), fminf(red[2],red[3]));
  __syncthreads();
  return r;
}

// ---- stats init ----
__global__ void init_kernel(float* __restrict__ ST){
  int i = blockIdx.x * 256 + threadIdx.x;
  if (i >= 32768) return;
  ST[i] = (i >= 16384 && i < 18432) ? 3.402823466e38f : 0.0f;
}

// per-column |w| max (raw, atomic across row-chunks of 128)
__global__ void colamax_kernel(const float* __restrict__ w, int K, int N, float* __restrict__ raw){
  int c = blockIdx.x * 256 + threadIdx.x;
  if (c >= N) return;
  int r0 = blockIdx.y * 128;
  float m = 0.0f;
  for (int r = r0; r < r0 + 128; ++r) m = fmaxf(m, fabsf(w[(size_t)r * N + c]));
  atomicMaxF(&raw[c], m);
}

__global__ void finalize_kernel(float* __restrict__ p, int n){
  int i = blockIdx.x * 256 + threadIdx.x;
  if (i < n) p[i] = fmaxf(p[i] * (1.0f/127.0f), 1e-6f);
}

// LayerNorm (row of 1024) + striped amax of output
__global__ void ln_kernel(const float* __restrict__ x, const float* __restrict__ g,
                          const float* __restrict__ bb, float* __restrict__ out,
                          float* __restrict__ stripe){
  int row = blockIdx.x, tid = threadIdx.x;
  const float* xr = x + (size_t)row * DIM;
  float v[4];
#pragma unroll
  for (int i = 0; i < 4; i++) v[i] = xr[tid + i*256];
  float s = (v[0]+v[1]) + (v[2]+v[3]);
  s = block_reduce256<0>(s);
  float mean = s * (1.0f/DIM);
  float sq = 0.f;
#pragma unroll
  for (int i = 0; i < 4; i++){ float d = v[i]-mean; sq += d*d; }
  sq = block_reduce256<0>(sq);
  float inv = 1.0f / sqrtf(sq * (1.0f/DIM) + 1e-6f);
  float am = 0.f;
  float* orow = out + (size_t)row * DIM;
#pragma unroll
  for (int i = 0; i < 4; i++){
    int c = tid + i*256;
    float o = (v[i]-mean)*inv*g[c] + bb[c];
    orow[c] = o;
    am = fmaxf(am, fabsf(o));
  }
  am = block_reduce256<1>(am);
  if (tid == 0) atomicMaxF(&stripe[(blockIdx.x & 63)*16], am);
}

__global__ void amax_kernel(const float* __restrict__ x, long n, float* __restrict__ stripe){
  long i = (long)blockIdx.x * 256 + threadIdx.x;
  long st = (long)gridDim.x * 256;
  float m = 0.f;
  for (; i < n; i += st) m = fmaxf(m, fabsf(x[i]));
  m = block_reduce256<1>(m);
  if (threadIdx.x == 0) atomicMaxF(&stripe[(blockIdx.x & 63)*16], m);
}

// elementwise quantize to integer-valued bf16
__global__ void quant_kernel(const float* __restrict__ in, bf16* __restrict__ outq,
                             const float* __restrict__ stripe, float* __restrict__ scale_out, long n){
  float s = fmaxf(stripe_max(stripe) * (1.0f/127.0f), 1e-6f);
  long i = (long)blockIdx.x * 256 + threadIdx.x;
  if (i == 0) scale_out[0] = s;
  long st = (long)gridDim.x * 256;
  for (; i < n; i += st){
    float q = rintf(fminf(fmaxf(in[i] / s, -127.0f), 127.0f));
    outq[i] = __float2bfloat16(q);
  }
}

// weight quantize + transpose: w[K][N] -> wqT[N][K]
__global__ void transq_kernel(const float* __restrict__ w, bf16* __restrict__ wqT,
                              const float* __restrict__ scales, int K, int N){
  __shared__ float tile[32][33];
  int c0 = blockIdx.x * 32, r0 = blockIdx.y * 32;
  int tx = threadIdx.x, ty = threadIdx.y;   // (32,8)
#pragma unroll
  for (int i = 0; i < 4; i++){
    int r = ty + i*8;
    tile[r][tx] = w[(size_t)(r0 + r) * N + c0 + tx];
  }
  __syncthreads();
#pragma unroll
  for (int i = 0; i < 4; i++){
    int cl = ty + i*8;
    float s = scales[c0 + cl];
    float q = rintf(fminf(fmaxf(tile[tx][cl] / s, -127.0f), 127.0f));
    wqT[(size_t)(c0 + cl) * K + r0 + tx] = __float2bfloat16(q);
  }
}

// V quantize + transpose: v f32 (B,S,H,DH) -> vqT bf16 (B*H, DH, S)
__global__ void vtransq_kernel(const float* __restrict__ v, bf16* __restrict__ vqT,
                               const float* __restrict__ stripe, float* __restrict__ scale_out){
  __shared__ float tile[64][65];
  float s = fmaxf(stripe_max(stripe) * (1.0f/127.0f), 1e-6f);
  int tx = threadIdx.x, ty = threadIdx.y;   // (64,8)
  int bh = blockIdx.y, j0 = blockIdx.x * 64;
  int b = bh >> 4, h = bh & 15;
  if (blockIdx.x == 0 && bh == 0 && tx == 0 && ty == 0) scale_out[0] = s;
#pragma unroll
  for (int i = 0; i < 8; i++){
    int j = j0 + ty + i*8;
    tile[ty + i*8][tx] = v[((size_t)((size_t)b*SEQ + j)*NHEAD + h)*DHEAD + tx];
  }
  __syncthreads();
#pragma unroll
  for (int i = 0; i < 8; i++){
    int d = ty + i*8;
    float q = rintf(fminf(fmaxf(tile[tx][d] / s, -127.0f), 127.0f));
    vqT[((size_t)bh*DHEAD + d)*SEQ + j0 + tx] = __float2bfloat16(q);
  }
}

// SELF-ATTN fused softmax+quantize (min_l == 1.0 exactly -> sp = 1/127)
__global__ void softprobsq_kernel(const float* __restrict__ logits,
                                  float* __restrict__ scale_out, bf16* __restrict__ pq){
  int row = blockIdx.x, tid = threadIdx.x;
  const float* lr = logits + (size_t)row * SEQ;
  float a = lr[tid], b = lr[tid + 256];
  float m = block_reduce256<1>(fmaxf(a, b));
  float ea = expf(a - m), eb = expf(b - m);
  float l = block_reduce256<0>(ea + eb);
  const float sp = 1.0f/127.0f;
  if (row == 0 && tid == 0) scale_out[0] = sp;
  float inv = 1.0f / l;
  float qa = rintf(fminf(fmaxf((ea*inv) / sp, -127.0f), 127.0f));
  float qb = rintf(fminf(fmaxf((eb*inv) / sp, -127.0f), 127.0f));
  pq[(size_t)row*SEQ + tid]       = __float2bfloat16(qa);
  pq[(size_t)row*SEQ + tid + 256] = __float2bfloat16(qb);
}

// CROSS-ATTN pass 1: row stats only
__global__ void softstats_kernel(const float* __restrict__ logits, float* __restrict__ mrow,
                                 float* __restrict__ lrow){
  int row = blockIdx.x, tid = threadIdx.x;
  const float* lr = logits + (size_t)row * SEQ;
  float a = lr[tid], b = lr[tid + 256];
  float m = block_reduce256<1>(fmaxf(a, b));
  float l = block_reduce256<0>(expf(a - m) + expf(b - m));
  if (tid == 0){ mrow[row] = m; lrow[row] = l; }
}

// reduce min over lrow[0..n) into 64 stripe slots
__global__ void minl_kernel(const float* __restrict__ lrow, int n, float* __restrict__ stripe){
  float v = 3.402823466e38f;
  for (int i = blockIdx.x * 256 + threadIdx.x; i < n; i += 64*256) v = fminf(v, lrow[i]);
  v = block_reduce256<2>(v);
  if (threadIdx.x == 0) stripe[blockIdx.x*16] = v;
}

// CROSS-ATTN pass 2
__global__ void probsq_kernel(const float* __restrict__ logits, const float* __restrict__ mrow,
                              const float* __restrict__ lrow, const float* __restrict__ minl_stripe,
                              float* __restrict__ scale_out, bf16* __restrict__ pq){
  int row = blockIdx.x, tid = threadIdx.x;
  float sp = fmaxf((1.0f/stripe_min(minl_stripe)) * (1.0f/127.0f), 1e-6f);
  if (row == 0 && tid == 0) scale_out[0] = sp;
  float m = mrow[row], l = lrow[row];
#pragma unroll
  for (int k = 0; k < 2; k++){
    int j = tid + k*256;
    float p = expf(logits[(size_t)row*SEQ + j] - m) / l;
    float q = rintf(fminf(fmaxf(p / sp, -127.0f), 127.0f));
    pq[(size_t)row*SEQ + j] = __float2bfloat16(q);
  }
}

// ---------------- MFMA GEMM (TM x TN tile, async dbuf, XCD-swizzled) -------
// 4 waves in 2x2; wave tile (TM/2)x(TN/2); FI=TM/32, FJ=TN/32 frags.
// SPLITN: N in 1024-col chunks; chunk c -> C + c*oCchunk, ldc=1024; post on
// chunk 0 only; amax stripe per chunk (+c*1024). Tiles never straddle chunks.
template<int BK, int TM, int TN, int RESID, bool CAUSAL, bool RELU, bool HASBIAS, bool HASAMAX, bool SPLITN>
__global__ __launch_bounds__(256) void gemm_kernel(
    const bf16* __restrict__ A, const bf16* __restrict__ Bt,
    float* __restrict__ C, const float* __restrict__ R,
    const float* __restrict__ sAp, const float* __restrict__ sBp, int sBstride,
    const float* __restrict__ bias, float post, float* __restrict__ amax_stripe,
    int Mdim, int Ndim, int Kdim, int lda, int ldb, int ldc,
    long oA1, long oA2, long oB1, long oB2, long oC1, long oC2, long oCchunk)
{
  const int FI = TM/32, FJ = TN/32;
  __shared__ __align__(16) bf16 As[2][TM*BK];
  __shared__ __align__(16) bf16 Bs[2][TN*BK];
  int z = blockIdx.z;
  long offA = (long)(z >> 4)*oA1 + (long)(z & 15)*oA2;
  long offB = (long)(z >> 4)*oB1 + (long)(z & 15)*oB2;
  long offC = (long)(z >> 4)*oC1 + (long)(z & 15)*oC2;
  const bf16* Ab = A + offA;
  const bf16* Bb = Bt + offB;
  int tid = threadIdx.x;
  int lane = tid & 63, wid = tid >> 6;
  int wr = wid >> 1, wc = wid & 1;

  // XCD-aware swizzle: round-robin linear-id -> give XCD k a row band.
  int bx = blockIdx.x, by = blockIdx.y;
  if ((gridDim.y & 7) == 0){
    int lin  = by * gridDim.x + bx;
    int xcd  = lin & 7, slot = lin >> 3;
    int bandH = gridDim.y >> 3;
    by = xcd * bandH + (slot % bandH);
    bx = slot / bandH;
  }
  int m0 = by * TM, n0 = bx * TN;

  floatx4 acc[FI][FJ];
#pragma unroll
  for (int i = 0; i < FI; i++)
#pragma unroll
    for (int j = 0; j < FJ; j++){ floatx4 zv = {0.f,0.f,0.f,0.f}; acc[i][j] = zv; }

  const int PIECES = BK/8;             // 16B pieces per row
  const int SLOTSA = TM*PIECES;
  const int SLOTSB = TN*PIECES;
  bool skip = CAUSAL && (n0 > m0 + TM - 1);

  auto stage = [&](int kt, int buf){
#pragma unroll
    for (int s = tid; s < SLOTSA; s += 256){
      int row = s / PIECES, pc = s % PIECES;
      int gm = m0 + row; if (gm > Mdim-1) gm = Mdim-1;
      gld16(&As[buf][s*8], Ab + (size_t)gm*lda + kt + pc*8);
    }
#pragma unroll
    for (int s = tid; s < SLOTSB; s += 256){
      int row = s / PIECES, pc = s % PIECES;
      int gn = n0 + row; if (gn > Ndim-1) gn = Ndim-1;
      gld16(&Bs[buf][s*8], Bb + (size_t)gn*ldb + kt + pc*8);
    }
  };

  if (!skip){
    stage(0, 0);
    __syncthreads();
    int nIter = Kdim / BK;
    for (int it = 0; it < nIter; ++it){
      int cur = it & 1;
      if (it + 1 < nIter) stage((it+1)*BK, cur ^ 1);   // async prefetch overlaps MFMA
      const bf16* Ac = As[cur];
      const bf16* Bc = Bs[cur];
#pragma unroll
      for (int kk = 0; kk < BK; kk += 32){
        bf16x8 af[FI], bfr[FJ];
        int koff = kk + (lane >> 4)*8;
        int arow = wr*(TM/2) + (lane & 15);
#pragma unroll
        for (int i = 0; i < FI; i++) af[i] = *(const bf16x8*)(Ac + (arow + i*16)*BK + koff);
        int brow = wc*(TN/2) + (lane & 15);
#pragma unroll
        for (int j = 0; j < FJ; j++) bfr[j] = *(const bf16x8*)(Bc + (brow + j*16)*BK + koff);
#pragma unroll
        for (int i = 0; i < FI; i++)
#pragma unroll
          for (int j = 0; j < FJ; j++)
            acc[i][j] = __builtin_amdgcn_mfma_f32_16x16x32_bf16(af[i], bfr[j], acc[i][j], 0, 0, 0);
      }
      __syncthreads();
    }
  }

  // epilogue: C/D layout col=lane&15, row=(lane>>4)*4+reg
  float sA = sAp[0];
  float am = 0.0f;
  int colr = lane & 15, rowq = (lane >> 4)*4;
  int chunkId = 0;
  long cBase = offC;
  float postw = post;
  float* amaxS = amax_stripe;
  if (SPLITN){
    chunkId = n0 >> 10;
    cBase = (long)chunkId * oCchunk;
    postw = chunkId ? 1.0f : post;
    amaxS = amax_stripe + chunkId*1024;
  }
#pragma unroll
  for (int j = 0; j < FJ; j++){
    int n = n0 + wc*(TN/2) + j*16 + colr;
    int nc = n < Ndim ? n : Ndim-1;
    float sB = sBp[(size_t)nc * (size_t)sBstride];
    float cs = sA * sB * postw;
    float bv = HASBIAS ? bias[nc] : 0.0f;
    int ncol = SPLITN ? (n & 1023) : n;
#pragma unroll
    for (int i = 0; i < FI; i++){
      int mb = m0 + wr*(TM/2) + i*16 + rowq;
#pragma unroll
      for (int r = 0; r < 4; r++){
        int m = mb + r;
        float v = acc[i][j][r]*cs + bv;
        if (RELU) v = fmaxf(v, 0.0f);
        if (CAUSAL && n > m) v = -1e9f;
        if (m < Mdim && n < Ndim){
          size_t ci = (size_t)cBase + (size_t)m*ldc + ncol;
          if (RESID) v += R[ci];
          C[ci] = v;
          if (HASAMAX) am = fmaxf(am, fabsf(v));
        }
      }
    }
  }
  if (HASAMAX){
#pragma unroll
    for (int o = 32; o > 0; o >>= 1) am = fmaxf(am, __shfl_down(am, o));
    if (lane == 0){
      int j = (blockIdx.x*5 + blockIdx.y*11 + blockIdx.z*3 + wid) & 63;
      atomicMaxF(&amaxS[j*16], am);
    }
  }
}

// ---- attention drivers ----
static void run_attention_self(const bf16* AQb, const bf16* KQb, const bf16* VQTb,
                               float* BIGF, bf16* PQ, float* ao,
                               const float* sq, const float* sk, const float* sv,
                               float* pscale, float* amax_ao_stripe, hipStream_t stream)
{
  const long CH_A = (long)4*SEQ*DIM;
  const long CH_V = (long)64*DHEAD*SEQ;
  const int  CH_ROWS = 64*SEQ;                    // 32768
  for (int c = 0; c < 2; ++c){
    gemm_kernel<64,128,128,0,true,false,false,false,false><<<dim3(4,4,64),256,0,stream>>>(
      AQb + c*CH_A, KQb + c*CH_A, BIGF, nullptr, sq, sk, 0, nullptr, 1.0f, nullptr,
      SEQ, SEQ, DHEAD, DIM, DIM, SEQ,
      (long)SEQ*DIM, (long)DHEAD, (long)SEQ*DIM, (long)DHEAD,
      (long)NHEAD*SEQ*SEQ, (long)SEQ*SEQ, 0);
    softprobsq_kernel<<<dim3(CH_ROWS),256,0,stream>>>(BIGF, pscale, PQ);
    gemm_kernel<64,64,64,0,false,false,false,true,false><<<dim3(1,8,64),256,0,stream>>>(
      PQ, VQTb + c*CH_V, ao + c*CH_A, nullptr, pscale, sv, 0, nullptr, 1.0f, amax_ao_stripe,
      SEQ, DHEAD, SEQ, SEQ, SEQ, DIM,
      (long)NHEAD*SEQ*SEQ, (long)SEQ*SEQ, (long)NHEAD*DHEAD*SEQ, (long)DHEAD*SEQ,
      (long)SEQ*DIM, (long)DHEAD, 0);
  }
}

static void run_attention_cross(const bf16* AQb, const bf16* KQb, const bf16* VQTb,
                                float* BIGF, bf16* PQ, float* ao,
                                const float* sq, const float* sk, const float* sv,
                                float* pscale, float* minl_stripe, float* mrow, float* lrow,
                                float* amax_ao_stripe, hipStream_t stream)
{
  const long CH_A = (long)4*SEQ*DIM;
  const long CH_V = (long)64*DHEAD*SEQ;
  const int  CH_ROWS = 64*SEQ;
  auto qk = [&](int c){
    gemm_kernel<64,128,128,0,false,false,false,false,false><<<dim3(4,4,64),256,0,stream>>>(
      AQb + c*CH_A, KQb + c*CH_A, BIGF, nullptr, sq, sk, 0, nullptr, 1.0f, nullptr,
      SEQ, SEQ, DHEAD, DIM, DIM, SEQ,
      (long)SEQ*DIM, (long)DHEAD, (long)SEQ*DIM, (long)DHEAD,
      (long)NHEAD*SEQ*SEQ, (long)SEQ*SEQ, 0);
  };
  auto pv = [&](int c){
    gemm_kernel<64,64,64,0,false,false,false,true,false><<<dim3(1,8,64),256,0,stream>>>(
      PQ, VQTb + c*CH_V, ao + c*CH_A, nullptr, pscale, sv, 0, nullptr, 1.0f, amax_ao_stripe,
      SEQ, DHEAD, SEQ, SEQ, SEQ, DIM,
      (long)NHEAD*SEQ*SEQ, (long)SEQ*SEQ, (long)NHEAD*DHEAD*SEQ, (long)DHEAD*SEQ,
      (long)SEQ*DIM, (long)DHEAD, 0);
  };
  qk(0); softstats_kernel<<<dim3(CH_ROWS),256,0,stream>>>(BIGF, mrow, lrow);
  qk(1); softstats_kernel<<<dim3(CH_ROWS),256,0,stream>>>(BIGF, mrow + CH_ROWS, lrow + CH_ROWS);
  minl_kernel<<<dim3(64),256,0,stream>>>(lrow, NROW, minl_stripe);
  // chunk 1 logits still resident in BIGF
  probsq_kernel<<<dim3(CH_ROWS),256,0,stream>>>(BIGF, mrow + CH_ROWS, lrow + CH_ROWS,
                                                minl_stripe, pscale, PQ);
  pv(1);
  qk(0);
  probsq_kernel<<<dim3(CH_ROWS),256,0,stream>>>(BIGF, mrow, lrow, minl_stripe, pscale, PQ);
  pv(0);
}

extern "C" void kernel_launch(void* const* d_in, const int* in_sizes, int n_in,
                              void* d_out, int out_size, void* d_ws, size_t ws_size,
                              hipStream_t stream)
{
  (void)in_sizes; (void)n_in; (void)out_size; (void)ws_size;
  const float* targets = (const float*)d_in[0];
  const float* encoded = (const float*)d_in[1];
  const float* ln1_s = (const float*)d_in[4];
  const float* ln1_b = (const float*)d_in[5];
  const float* ln2_s = (const float*)d_in[6];
  const float* ln2_b = (const float*)d_in[7];
  const float* ln3_s = (const float*)d_in[8];
  const float* ln3_b = (const float*)d_in[9];
  const float* Wq_s = (const float*)d_in[10];
  const float* Wk_s = (const float*)d_in[11];
  const float* Wv_s = (const float*)d_in[12];
  const float* Wo_s = (const float*)d_in[13];
  const float* Wq_c = (const float*)d_in[14];
  const float* Wk_c = (const float*)d_in[15];
  const float* Wv_c = (const float*)d_in[16];
  const float* Wo_c = (const float*)d_in[17];
  const float* W1 = (const float*)d_in[18];
  const float* B1 = (const float*)d_in[19];
  const float* W2 = (const float*)d_in[20];
  const float* B2 = (const float*)d_in[21];
  float* OUT = (float*)d_out;

  char* ws = (char*)d_ws;
  const size_t MB = 1ull << 20;
  float* ACT_N = (float*)(ws +   0*MB);   // 16 MB  ln out; attn out
  float* ACT_Q = (float*)(ws +  16*MB);   // 16 MB
  float* ACT_K = (float*)(ws +  32*MB);   // 16 MB
  float* ACT_V = (float*)(ws +  48*MB);   // 16 MB
  float* BIGF  = (float*)(ws +  16*MB);   // 64 MB  logits chunk / mlp hidden (overlays Q/K/V)
  float* RES_X = (float*)(ws +  80*MB);   // 16 MB  x, then y (in-place)
  bf16*  XQ    = (bf16*) (ws +  96*MB);   // 32 MB  quantized act / P / h1
  bf16*  WQb   = (bf16*) (ws + 128*MB);   //  8 MB  quantized transposed weights
  bf16*  AQ    = (bf16*) (ws + 136*MB);   //  8 MB
  bf16*  KQ    = (bf16*) (ws + 144*MB);   //  8 MB
  bf16*  VQT   = (bf16*) (ws + 152*MB);   //  8 MB
  float* ST    = (float*)(ws + 160*MB);   //  1 MB  stripes + scales + row stats

  enum { XN=0, Q1=1, K1=2, V1=3, AO1=4, YN=5, Q2=6, K2=7, V2=8, AO2=9, ZN=10, H1S=11, ENC=12, P1=13, P2=14, MNL_C=17 };
  float* STR  = ST;                       // 18*1024 floats of stripes
  float* scl  = ST + 18432;               // 32 final scales
  float* wsc  = ST + 18496;               // 13312 per-column weight scales
  float* mrow = ST + 32768;
  float* lrow = ST + 98304;
#define STRIPE(s) (STR + (s)*1024)

  const long nAct = (long)NTOK * DIM;   // 4M elems

  init_kernel<<<dim3(128),256,0,stream>>>(ST);

  colamax_kernel<<<dim3( 4, 8),256,0,stream>>>(Wq_s, DIM, DIM, wsc +     0);
  colamax_kernel<<<dim3( 4, 8),256,0,stream>>>(Wk_s, DIM, DIM, wsc +  1024);
  colamax_kernel<<<dim3( 4, 8),256,0,stream>>>(Wv_s, DIM, DIM, wsc +  2048);
  colamax_kernel<<<dim3( 4, 8),256,0,stream>>>(Wo_s, DIM, DIM, wsc +  3072);
  colamax_kernel<<<dim3( 4, 8),256,0,stream>>>(Wq_c, DIM, DIM, wsc +  4096);
  colamax_kernel<<<dim3( 4, 8),256,0,stream>>>(Wk_c, DIM, DIM, wsc +  5120);
  colamax_kernel<<<dim3( 4, 8),256,0,stream>>>(Wv_c, DIM, DIM, wsc +  6144);
  colamax_kernel<<<dim3( 4, 8),256,0,stream>>>(Wo_c, DIM, DIM, wsc +  7168);
  colamax_kernel<<<dim3(16, 8),256,0,stream>>>(W1,   DIM, FF,  wsc +  8192);
  colamax_kernel<<<dim3( 4,32),256,0,stream>>>(W2,   FF,  DIM, wsc + 12288);
  finalize_kernel<<<dim3(52),256,0,stream>>>(wsc, 13312);

  // ================= self attention =================
  ln_kernel<<<dim3(NTOK),256,0,stream>>>(targets, ln1_s, ln1_b, ACT_N, STRIPE(XN));
  quant_kernel<<<dim3(4096),256,0,stream>>>(ACT_N, XQ, STRIPE(XN), &scl[XN], nAct);

  // fused QKV weights: wqT rows [0,1024)=Wq, [1024,2048)=Wk, [2048,3072)=Wv
  transq_kernel<<<dim3(32,32),dim3(32,8),0,stream>>>(Wq_s, WQb,             wsc +    0, DIM, DIM);
  transq_kernel<<<dim3(32,32),dim3(32,8),0,stream>>>(Wk_s, WQb + 1024*DIM,  wsc + 1024, DIM, DIM);
  transq_kernel<<<dim3(32,32),dim3(32,8),0,stream>>>(Wv_s, WQb + 2048*DIM,  wsc + 2048, DIM, DIM);
  gemm_kernel<64,128,64,0,false,false,false,true,true><<<dim3(48,32,1),256,0,stream>>>(
      XQ, WQb, ACT_Q, nullptr, &scl[XN], wsc + 0, 1, nullptr, 0.125f, STRIPE(Q1),
      NTOK, 3072, DIM, DIM, DIM, DIM, 0,0,0,0,0,0, nAct);

  quant_kernel<<<dim3(4096),256,0,stream>>>(ACT_Q, AQ, STRIPE(Q1), &scl[Q1], nAct);
  quant_kernel<<<dim3(4096),256,0,stream>>>(ACT_K, KQ, STRIPE(K1), &scl[K1], nAct);
  vtransq_kernel<<<dim3(8,128),dim3(64,8),0,stream>>>(ACT_V, VQT, STRIPE(V1), &scl[V1]);

  run_attention_self(AQ, KQ, VQT, BIGF, XQ, ACT_N,
                     &scl[Q1], &scl[K1], &scl[V1], &scl[P1], STRIPE(AO1), stream);

  quant_kernel<<<dim3(4096),256,0,stream>>>(ACT_N, XQ, STRIPE(AO1), &scl[AO1], nAct);
  transq_kernel<<<dim3(32,32),dim3(32,8),0,stream>>>(Wo_s, WQb, wsc + 3072, DIM, DIM);
  gemm_kernel<64,128,64,1,false,false,false,false,false><<<dim3(16,32,1),256,0,stream>>>(
      XQ, WQb, RES_X, targets, &scl[AO1], wsc + 3072, 1, nullptr, 1.0f, nullptr,
      NTOK, DIM, DIM, DIM, DIM, DIM, 0,0,0,0,0,0, 0);

  // ================= cross attention =================
  ln_kernel<<<dim3(NTOK),256,0,stream>>>(RES_X, ln2_s, ln2_b, ACT_N, STRIPE(YN));
  quant_kernel<<<dim3(4096),256,0,stream>>>(ACT_N, XQ, STRIPE(YN), &scl[YN], nAct);
  amax_kernel<<<dim3(2048),256,0,stream>>>(encoded, nAct, STRIPE(ENC));
  quant_kernel<<<dim3(4096),256,0,stream>>>(encoded, AQ, STRIPE(ENC), &scl[ENC], nAct);

  transq_kernel<<<dim3(32,32),dim3(32,8),0,stream>>>(Wq_c, WQb,            wsc + 4096, DIM, DIM);
  transq_kernel<<<dim3(32,32),dim3(32,8),0,stream>>>(Wk_c, WQb + 1024*DIM, wsc + 5120, DIM, DIM);
  transq_kernel<<<dim3(32,32),dim3(32,8),0,stream>>>(Wv_c, WQb + 2048*DIM, wsc + 6144, DIM, DIM);
  gemm_kernel<64,128,64,0,false,false,false,true,false><<<dim3(16,32,1),256,0,stream>>>(
      XQ, WQb, ACT_Q, nullptr, &scl[YN], wsc + 4096, 1, nullptr, 0.125f, STRIPE(Q2),
      NTOK, DIM, DIM, DIM, DIM, DIM, 0,0,0,0,0,0, 0);
  // fused KV (A = quantized encoded): chunks -> ACT_K, ACT_V
  gemm_kernel<64,128,64,0,false,false,false,true,true><<<dim3(32,32,1),256,0,stream>>>(
      AQ, WQb + 1024*DIM, ACT_K, nullptr, &scl[ENC], wsc + 5120, 1, nullptr, 1.0f, STRIPE(K2),
      NTOK, 2048, DIM, DIM, DIM, DIM, 0,0,0,0,0,0, nAct);

  quant_kernel<<<dim3(4096),256,0,stream>>>(ACT_Q, AQ, STRIPE(Q2), &scl[Q2], nAct);
  quant_kernel<<<dim3(4096),256,0,stream>>>(ACT_K, KQ, STRIPE(K2), &scl[K2], nAct);
  vtransq_kernel<<<dim3(8,128),dim3(64,8),0,stream>>>(ACT_V, VQT, STRIPE(V2), &scl[V2]);

  run_attention_cross(AQ, KQ, VQT, BIGF, XQ, ACT_N,
                      &scl[Q2], &scl[K2], &scl[V2], &scl[P2], STRIPE(MNL_C),
                      mrow, lrow, STRIPE(AO2), stream);

  quant_kernel<<<dim3(4096),256,0,stream>>>(ACT_N, XQ, STRIPE(AO2), &scl[AO2], nAct);
  transq_kernel<<<dim3(32,32),dim3(32,8),0,stream>>>(Wo_c, WQb, wsc + 7168, DIM, DIM);
  gemm_kernel<64,128,64,1,false,false,false,false,false><<<dim3(16,32,1),256,0,stream>>>(
      XQ, WQb, RES_X, RES_X, &scl[AO2], wsc + 7168, 1, nullptr, 1.0f, nullptr,
      NTOK, DIM, DIM, DIM, DIM, DIM, 0,0,0,0,0,0, 0);

  // ================= MLP =================
  ln_kernel<<<dim3(NTOK),256,0,stream>>>(RES_X, ln3_s, ln3_b, ACT_N, STRIPE(ZN));
  quant_kernel<<<dim3(4096),256,0,stream>>>(ACT_N, XQ, STRIPE(ZN), &scl[ZN], nAct);
  transq_kernel<<<dim3(128,32),dim3(32,8),0,stream>>>(W1, WQb, wsc + 8192, DIM, FF);
  gemm_kernel<64,128,64,0,false,true,true,true,false><<<dim3(64,32,1),256,0,stream>>>(
      XQ, WQb, BIGF, nullptr, &scl[ZN], wsc + 8192, 1, B1, 1.0f, STRIPE(H1S),
      NTOK, FF, DIM, DIM, DIM, FF, 0,0,0,0,0,0, 0);
  quant_kernel<<<dim3(8192),256,0,stream>>>(BIGF, XQ, STRIPE(H1S), &scl[H1S], (long)NTOK*FF);
  transq_kernel<<<dim3(32,128),dim3(32,8),0,stream>>>(W2, WQb, wsc + 12288, FF, DIM);
  gemm_kernel<64,128,64,1,false,false,true,false,false><<<dim3(16,32,1),256,0,stream>>>(
      XQ, WQb, OUT, RES_X, &scl[H1S], wsc + 12288, 1, B2, 1.0f, nullptr,
      NTOK, DIM, FF, FF, FF, DIM, 0,0,0,0,0,0, 0);
}

// Round 8
// 1424.851 us; speedup vs baseline: 1.0509x; 1.0509x over previous
//
// EncoderDecoder1DBlock on MI355X (gfx950).
// Int8 fake-quant reproduced EXACTLY via integer-valued bf16 MFMA GEMMs.
// R8: LDS XOR swizzle. R7 showed SQ_LDS_BANK_CONFLICT 1.9e7: BK=64 row
// stride = 32 banks -> quarter-wave ds_read_b128 is 16-way conflicted.
// global_load_lds forbids padding (lane->base+lane*16), but content is free:
// LDS slot (row,pc) holds global piece pc^(row&7); readers use the inverse.
// Banks per quarter-wave become (p^(lane&7))*4 -> 2-way = free (m136).
// Keeps R7 128x64/BK=64 tiles + XCD row-band swizzle.
// Workspace: 161 MB.

#include <hip/hip_runtime.h>
#include <hip/hip_bf16.h>

typedef __hip_bfloat16 bf16;
typedef __attribute__((ext_vector_type(8))) short bf16x8;   // 8 bf16 = 4 VGPRs
typedef __attribute__((ext_vector_type(4))) float floatx4;

#define NBATCH 8
#define SEQ    512
#define DIM    1024
#define NHEAD  16
#define DHEAD  64
#define FF     4096
#define NTOK   (NBATCH*SEQ)            // 4096
#define NROW   (NBATCH*NHEAD*SEQ)      // 65536 attention rows

__device__ inline void atomicMaxF(float* p, float v){ atomicMax((unsigned int*)p, __float_as_uint(v)); } // v >= 0

// async global->LDS, 16 bytes per lane (LDS dest = wave-uniform base + lane*16)
__device__ inline void gld16(bf16* lds, const bf16* g){
  __builtin_amdgcn_global_load_lds(
      (const __attribute__((address_space(1))) void*)g,
      (__attribute__((address_space(3))) void*)lds, 16, 0, 0);
}

// ---- 64-way stripe: sub-slot j lives at stripe[j*16] (64B apart) ----
__device__ inline float stripe_max(const float* __restrict__ st){
  float v = st[(threadIdx.x & 63)*16];
#pragma unroll
  for (int o = 32; o > 0; o >>= 1) v = fmaxf(v, __shfl_xor(v, o));
  return v;
}
__device__ inline float stripe_min(const float* __restrict__ st){
  float v = st[(threadIdx.x & 63)*16];
#pragma unroll
  for (int o = 32; o > 0; o >>= 1) v = fminf(v, __shfl_xor(v, o));
  return v;
}

// blockDim.x == 256 assumed (4 waves). OP: 0=sum, 1=max, 2=min
template<int OP>
__device__ inline float block_reduce256(float v){
  __shared__ float red[4];
#pragma unroll
  for (int o = 32; o > 0; o >>= 1){
    float t = __shfl_down(v, o);
    v = OP==0 ? v + t : (OP==1 ? fmaxf(v, t) : fminf(v, t));
  }
  int lane = threadIdx.x & 63, w = threadIdx.x >> 6;
  if (lane == 0) red[w] = v;
  __syncthreads();
  float r = OP==0 ? (red[0]+red[1])+(red[2]+red[3])
          : OP==1 ? fmaxf(fmaxf(red[0],red[1]), fmaxf(red[2],red[3]))
                  : fminf(fminf(red[0],red[1]), fminf(red[2],red[3]));
  __syncthreads();
  return r;
}

// ---- stats init ----
__global__ void init_kernel(float* __restrict__ ST){
  int i = blockIdx.x * 256 + threadIdx.x;
  if (i >= 32768) return;
  ST[i] = (i >= 16384 && i < 18432) ? 3.402823466e38f : 0.0f;
}

// per-column |w| max (raw, atomic across row-chunks of 128)
__global__ void colamax_kernel(const float* __restrict__ w, int K, int N, float* __restrict__ raw){
  int c = blockIdx.x * 256 + threadIdx.x;
  if (c >= N) return;
  int r0 = blockIdx.y * 128;
  float m = 0.0f;
  for (int r = r0; r < r0 + 128; ++r) m = fmaxf(m, fabsf(w[(size_t)r * N + c]));
  atomicMaxF(&raw[c], m);
}

__global__ void finalize_kernel(float* __restrict__ p, int n){
  int i = blockIdx.x * 256 + threadIdx.x;
  if (i < n) p[i] = fmaxf(p[i] * (1.0f/127.0f), 1e-6f);
}

// LayerNorm (row of 1024) + striped amax of output
__global__ void ln_kernel(const float* __restrict__ x, const float* __restrict__ g,
                          const float* __restrict__ bb, float* __restrict__ out,
                          float* __restrict__ stripe){
  int row = blockIdx.x, tid = threadIdx.x;
  const float* xr = x + (size_t)row * DIM;
  float v[4];
#pragma unroll
  for (int i = 0; i < 4; i++) v[i] = xr[tid + i*256];
  float s = (v[0]+v[1]) + (v[2]+v[3]);
  s = block_reduce256<0>(s);
  float mean = s * (1.0f/DIM);
  float sq = 0.f;
#pragma unroll
  for (int i = 0; i < 4; i++){ float d = v[i]-mean; sq += d*d; }
  sq = block_reduce256<0>(sq);
  float inv = 1.0f / sqrtf(sq * (1.0f/DIM) + 1e-6f);
  float am = 0.f;
  float* orow = out + (size_t)row * DIM;
#pragma unroll
  for (int i = 0; i < 4; i++){
    int c = tid + i*256;
    float o = (v[i]-mean)*inv*g[c] + bb[c];
    orow[c] = o;
    am = fmaxf(am, fabsf(o));
  }
  am = block_reduce256<1>(am);
  if (tid == 0) atomicMaxF(&stripe[(blockIdx.x & 63)*16], am);
}

__global__ void amax_kernel(const float* __restrict__ x, long n, float* __restrict__ stripe){
  long i = (long)blockIdx.x * 256 + threadIdx.x;
  long st = (long)gridDim.x * 256;
  float m = 0.f;
  for (; i < n; i += st) m = fmaxf(m, fabsf(x[i]));
  m = block_reduce256<1>(m);
  if (threadIdx.x == 0) atomicMaxF(&stripe[(blockIdx.x & 63)*16], m);
}

// elementwise quantize to integer-valued bf16
__global__ void quant_kernel(const float* __restrict__ in, bf16* __restrict__ outq,
                             const float* __restrict__ stripe, float* __restrict__ scale_out, long n){
  float s = fmaxf(stripe_max(stripe) * (1.0f/127.0f), 1e-6f);
  long i = (long)blockIdx.x * 256 + threadIdx.x;
  if (i == 0) scale_out[0] = s;
  long st = (long)gridDim.x * 256;
  for (; i < n; i += st){
    float q = rintf(fminf(fmaxf(in[i] / s, -127.0f), 127.0f));
    outq[i] = __float2bfloat16(q);
  }
}

// weight quantize + transpose: w[K][N] -> wqT[N][K]
__global__ void transq_kernel(const float* __restrict__ w, bf16* __restrict__ wqT,
                              const float* __restrict__ scales, int K, int N){
  __shared__ float tile[32][33];
  int c0 = blockIdx.x * 32, r0 = blockIdx.y * 32;
  int tx = threadIdx.x, ty = threadIdx.y;   // (32,8)
#pragma unroll
  for (int i = 0; i < 4; i++){
    int r = ty + i*8;
    tile[r][tx] = w[(size_t)(r0 + r) * N + c0 + tx];
  }
  __syncthreads();
#pragma unroll
  for (int i = 0; i < 4; i++){
    int cl = ty + i*8;
    float s = scales[c0 + cl];
    float q = rintf(fminf(fmaxf(tile[tx][cl] / s, -127.0f), 127.0f));
    wqT[(size_t)(c0 + cl) * K + r0 + tx] = __float2bfloat16(q);
  }
}

// V quantize + transpose: v f32 (B,S,H,DH) -> vqT bf16 (B*H, DH, S)
__global__ void vtransq_kernel(const float* __restrict__ v, bf16* __restrict__ vqT,
                               const float* __restrict__ stripe, float* __restrict__ scale_out){
  __shared__ float tile[64][65];
  float s = fmaxf(stripe_max(stripe) * (1.0f/127.0f), 1e-6f);
  int tx = threadIdx.x, ty = threadIdx.y;   // (64,8)
  int bh = blockIdx.y, j0 = blockIdx.x * 64;
  int b = bh >> 4, h = bh & 15;
  if (blockIdx.x == 0 && bh == 0 && tx == 0 && ty == 0) scale_out[0] = s;
#pragma unroll
  for (int i = 0; i < 8; i++){
    int j = j0 + ty + i*8;
    tile[ty + i*8][tx] = v[((size_t)((size_t)b*SEQ + j)*NHEAD + h)*DHEAD + tx];
  }
  __syncthreads();
#pragma unroll
  for (int i = 0; i < 8; i++){
    int d = ty + i*8;
    float q = rintf(fminf(fmaxf(tile[tx][d] / s, -127.0f), 127.0f));
    vqT[((size_t)bh*DHEAD + d)*SEQ + j0 + tx] = __float2bfloat16(q);
  }
}

// SELF-ATTN fused softmax+quantize (min_l == 1.0 exactly -> sp = 1/127)
__global__ void softprobsq_kernel(const float* __restrict__ logits,
                                  float* __restrict__ scale_out, bf16* __restrict__ pq){
  int row = blockIdx.x, tid = threadIdx.x;
  const float* lr = logits + (size_t)row * SEQ;
  float a = lr[tid], b = lr[tid + 256];
  float m = block_reduce256<1>(fmaxf(a, b));
  float ea = expf(a - m), eb = expf(b - m);
  float l = block_reduce256<0>(ea + eb);
  const float sp = 1.0f/127.0f;
  if (row == 0 && tid == 0) scale_out[0] = sp;
  float inv = 1.0f / l;
  float qa = rintf(fminf(fmaxf((ea*inv) / sp, -127.0f), 127.0f));
  float qb = rintf(fminf(fmaxf((eb*inv) / sp, -127.0f), 127.0f));
  pq[(size_t)row*SEQ + tid]       = __float2bfloat16(qa);
  pq[(size_t)row*SEQ + tid + 256] = __float2bfloat16(qb);
}

// CROSS-ATTN pass 1: row stats only
__global__ void softstats_kernel(const float* __restrict__ logits, float* __restrict__ mrow,
                                 float* __restrict__ lrow){
  int row = blockIdx.x, tid = threadIdx.x;
  const float* lr = logits + (size_t)row * SEQ;
  float a = lr[tid], b = lr[tid + 256];
  float m = block_reduce256<1>(fmaxf(a, b));
  float l = block_reduce256<0>(expf(a - m) + expf(b - m));
  if (tid == 0){ mrow[row] = m; lrow[row] = l; }
}

// reduce min over lrow[0..n) into 64 stripe slots
__global__ void minl_kernel(const float* __restrict__ lrow, int n, float* __restrict__ stripe){
  float v = 3.402823466e38f;
  for (int i = blockIdx.x * 256 + threadIdx.x; i < n; i += 64*256) v = fminf(v, lrow[i]);
  v = block_reduce256<2>(v);
  if (threadIdx.x == 0) stripe[blockIdx.x*16] = v;
}

// CROSS-ATTN pass 2
__global__ void probsq_kernel(const float* __restrict__ logits, const float* __restrict__ mrow,
                              const float* __restrict__ lrow, const float* __restrict__ minl_stripe,
                              float* __restrict__ scale_out, bf16* __restrict__ pq){
  int row = blockIdx.x, tid = threadIdx.x;
  float sp = fmaxf((1.0f/stripe_min(minl_stripe)) * (1.0f/127.0f), 1e-6f);
  if (row == 0 && tid == 0) scale_out[0] = sp;
  float m = mrow[row], l = lrow[row];
#pragma unroll
  for (int k = 0; k < 2; k++){
    int j = tid + k*256;
    float p = expf(logits[(size_t)row*SEQ + j] - m) / l;
    float q = rintf(fminf(fmaxf(p / sp, -127.0f), 127.0f));
    pq[(size_t)row*SEQ + j] = __float2bfloat16(q);
  }
}

// ------- MFMA GEMM (TM x TN tile, async dbuf, XCD + LDS-XOR swizzled) ------
// LDS layout: slot (row,pc) holds global piece pc^(row&(PIECES-1)); readers
// apply the inverse so quarter-wave ds_read_b128 banks spread 2-way (free).
template<int BK, int TM, int TN, int RESID, bool CAUSAL, bool RELU, bool HASBIAS, bool HASAMAX, bool SPLITN>
__global__ __launch_bounds__(256) void gemm_kernel(
    const bf16* __restrict__ A, const bf16* __restrict__ Bt,
    float* __restrict__ C, const float* __restrict__ R,
    const float* __restrict__ sAp, const float* __restrict__ sBp, int sBstride,
    const float* __restrict__ bias, float post, float* __restrict__ amax_stripe,
    int Mdim, int Ndim, int Kdim, int lda, int ldb, int ldc,
    long oA1, long oA2, long oB1, long oB2, long oC1, long oC2, long oCchunk)
{
  const int FI = TM/32, FJ = TN/32;
  const int PIECES = BK/8;             // 16B pieces per row
  const int PMASK  = PIECES - 1;
  __shared__ __align__(16) bf16 As[2][TM*BK];
  __shared__ __align__(16) bf16 Bs[2][TN*BK];
  int z = blockIdx.z;
  long offA = (long)(z >> 4)*oA1 + (long)(z & 15)*oA2;
  long offB = (long)(z >> 4)*oB1 + (long)(z & 15)*oB2;
  long offC = (long)(z >> 4)*oC1 + (long)(z & 15)*oC2;
  const bf16* Ab = A + offA;
  const bf16* Bb = Bt + offB;
  int tid = threadIdx.x;
  int lane = tid & 63, wid = tid >> 6;
  int wr = wid >> 1, wc = wid & 1;

  // XCD-aware swizzle: round-robin linear-id -> give XCD k a row band.
  int bx = blockIdx.x, by = blockIdx.y;
  if ((gridDim.y & 7) == 0){
    int lin  = by * gridDim.x + bx;
    int xcd  = lin & 7, slot = lin >> 3;
    int bandH = gridDim.y >> 3;
    by = xcd * bandH + (slot % bandH);
    bx = slot / bandH;
  }
  int m0 = by * TM, n0 = bx * TN;

  floatx4 acc[FI][FJ];
#pragma unroll
  for (int i = 0; i < FI; i++)
#pragma unroll
    for (int j = 0; j < FJ; j++){ floatx4 zv = {0.f,0.f,0.f,0.f}; acc[i][j] = zv; }

  const int SLOTSA = TM*PIECES;
  const int SLOTSB = TN*PIECES;
  bool skip = CAUSAL && (n0 > m0 + TM - 1);

  auto stage = [&](int kt, int buf){
#pragma unroll
    for (int s = tid; s < SLOTSA; s += 256){
      int row = s / PIECES, pc = s % PIECES;
      int gpc = pc ^ (row & PMASK);                 // XOR content swizzle
      int gm = m0 + row; if (gm > Mdim-1) gm = Mdim-1;
      gld16(&As[buf][s*8], Ab + (size_t)gm*lda + kt + gpc*8);
    }
#pragma unroll
    for (int s = tid; s < SLOTSB; s += 256){
      int row = s / PIECES, pc = s % PIECES;
      int gpc = pc ^ (row & PMASK);
      int gn = n0 + row; if (gn > Ndim-1) gn = Ndim-1;
      gld16(&Bs[buf][s*8], Bb + (size_t)gn*ldb + kt + gpc*8);
    }
  };

  if (!skip){
    stage(0, 0);
    __syncthreads();
    int nIter = Kdim / BK;
    int arow = wr*(TM/2) + (lane & 15);
    int brow = wc*(TN/2) + (lane & 15);
    int aswz = arow & PMASK;                        // invariant across i (16%PIECES==0)
    int bswz = brow & PMASK;
    for (int it = 0; it < nIter; ++it){
      int cur = it & 1;
      if (it + 1 < nIter) stage((it+1)*BK, cur ^ 1);   // async prefetch overlaps MFMA
      const bf16* Ac = As[cur];
      const bf16* Bc = Bs[cur];
#pragma unroll
      for (int kk = 0; kk < BK; kk += 32){
        bf16x8 af[FI], bfr[FJ];
        int p = (kk >> 3) + (lane >> 4);            // k-piece index
        int aoff = (p ^ aswz) * 8;
        int boff = (p ^ bswz) * 8;
#pragma unroll
        for (int i = 0; i < FI; i++) af[i] = *(const bf16x8*)(Ac + (arow + i*16)*BK + aoff);
#pragma unroll
        for (int j = 0; j < FJ; j++) bfr[j] = *(const bf16x8*)(Bc + (brow + j*16)*BK + boff);
#pragma unroll
        for (int i = 0; i < FI; i++)
#pragma unroll
          for (int j = 0; j < FJ; j++)
            acc[i][j] = __builtin_amdgcn_mfma_f32_16x16x32_bf16(af[i], bfr[j], acc[i][j], 0, 0, 0);
      }
      __syncthreads();
    }
  }

  // epilogue: C/D layout col=lane&15, row=(lane>>4)*4+reg
  float sA = sAp[0];
  float am = 0.0f;
  int colr = lane & 15, rowq = (lane >> 4)*4;
  int chunkId = 0;
  long cBase = offC;
  float postw = post;
  float* amaxS = amax_stripe;
  if (SPLITN){
    chunkId = n0 >> 10;
    cBase = (long)chunkId * oCchunk;
    postw = chunkId ? 1.0f : post;
    amaxS = amax_stripe + chunkId*1024;
  }
#pragma unroll
  for (int j = 0; j < FJ; j++){
    int n = n0 + wc*(TN/2) + j*16 + colr;
    int nc = n < Ndim ? n : Ndim-1;
    float sB = sBp[(size_t)nc * (size_t)sBstride];
    float cs = sA * sB * postw;
    float bv = HASBIAS ? bias[nc] : 0.0f;
    int ncol = SPLITN ? (n & 1023) : n;
#pragma unroll
    for (int i = 0; i < FI; i++){
      int mb = m0 + wr*(TM/2) + i*16 + rowq;
#pragma unroll
      for (int r = 0; r < 4; r++){
        int m = mb + r;
        float v = acc[i][j][r]*cs + bv;
        if (RELU) v = fmaxf(v, 0.0f);
        if (CAUSAL && n > m) v = -1e9f;
        if (m < Mdim && n < Ndim){
          size_t ci = (size_t)cBase + (size_t)m*ldc + ncol;
          if (RESID) v += R[ci];
          C[ci] = v;
          if (HASAMAX) am = fmaxf(am, fabsf(v));
        }
      }
    }
  }
  if (HASAMAX){
#pragma unroll
    for (int o = 32; o > 0; o >>= 1) am = fmaxf(am, __shfl_down(am, o));
    if (lane == 0){
      int j = (blockIdx.x*5 + blockIdx.y*11 + blockIdx.z*3 + wid) & 63;
      atomicMaxF(&amaxS[j*16], am);
    }
  }
}

// ---- attention drivers ----
static void run_attention_self(const bf16* AQb, const bf16* KQb, const bf16* VQTb,
                               float* BIGF, bf16* PQ, float* ao,
                               const float* sq, const float* sk, const float* sv,
                               float* pscale, float* amax_ao_stripe, hipStream_t stream)
{
  const long CH_A = (long)4*SEQ*DIM;
  const long CH_V = (long)64*DHEAD*SEQ;
  const int  CH_ROWS = 64*SEQ;                    // 32768
  for (int c = 0; c < 2; ++c){
    gemm_kernel<64,128,128,0,true,false,false,false,false><<<dim3(4,4,64),256,0,stream>>>(
      AQb + c*CH_A, KQb + c*CH_A, BIGF, nullptr, sq, sk, 0, nullptr, 1.0f, nullptr,
      SEQ, SEQ, DHEAD, DIM, DIM, SEQ,
      (long)SEQ*DIM, (long)DHEAD, (long)SEQ*DIM, (long)DHEAD,
      (long)NHEAD*SEQ*SEQ, (long)SEQ*SEQ, 0);
    softprobsq_kernel<<<dim3(CH_ROWS),256,0,stream>>>(BIGF, pscale, PQ);
    gemm_kernel<64,64,64,0,false,false,false,true,false><<<dim3(1,8,64),256,0,stream>>>(
      PQ, VQTb + c*CH_V, ao + c*CH_A, nullptr, pscale, sv, 0, nullptr, 1.0f, amax_ao_stripe,
      SEQ, DHEAD, SEQ, SEQ, SEQ, DIM,
      (long)NHEAD*SEQ*SEQ, (long)SEQ*SEQ, (long)NHEAD*DHEAD*SEQ, (long)DHEAD*SEQ,
      (long)SEQ*DIM, (long)DHEAD, 0);
  }
}

static void run_attention_cross(const bf16* AQb, const bf16* KQb, const bf16* VQTb,
                                float* BIGF, bf16* PQ, float* ao,
                                const float* sq, const float* sk, const float* sv,
                                float* pscale, float* minl_stripe, float* mrow, float* lrow,
                                float* amax_ao_stripe, hipStream_t stream)
{
  const long CH_A = (long)4*SEQ*DIM;
  const long CH_V = (long)64*DHEAD*SEQ;
  const int  CH_ROWS = 64*SEQ;
  auto qk = [&](int c){
    gemm_kernel<64,128,128,0,false,false,false,false,false><<<dim3(4,4,64),256,0,stream>>>(
      AQb + c*CH_A, KQb + c*CH_A, BIGF, nullptr, sq, sk, 0, nullptr, 1.0f, nullptr,
      SEQ, SEQ, DHEAD, DIM, DIM, SEQ,
      (long)SEQ*DIM, (long)DHEAD, (long)SEQ*DIM, (long)DHEAD,
      (long)NHEAD*SEQ*SEQ, (long)SEQ*SEQ, 0);
  };
  auto pv = [&](int c){
    gemm_kernel<64,64,64,0,false,false,false,true,false><<<dim3(1,8,64),256,0,stream>>>(
      PQ, VQTb + c*CH_V, ao + c*CH_A, nullptr, pscale, sv, 0, nullptr, 1.0f, amax_ao_stripe,
      SEQ, DHEAD, SEQ, SEQ, SEQ, DIM,
      (long)NHEAD*SEQ*SEQ, (long)SEQ*SEQ, (long)NHEAD*DHEAD*SEQ, (long)DHEAD*SEQ,
      (long)SEQ*DIM, (long)DHEAD, 0);
  };
  qk(0); softstats_kernel<<<dim3(CH_ROWS),256,0,stream>>>(BIGF, mrow, lrow);
  qk(1); softstats_kernel<<<dim3(CH_ROWS),256,0,stream>>>(BIGF, mrow + CH_ROWS, lrow + CH_ROWS);
  minl_kernel<<<dim3(64),256,0,stream>>>(lrow, NROW, minl_stripe);
  // chunk 1 logits still resident in BIGF
  probsq_kernel<<<dim3(CH_ROWS),256,0,stream>>>(BIGF, mrow + CH_ROWS, lrow + CH_ROWS,
                                                minl_stripe, pscale, PQ);
  pv(1);
  qk(0);
  probsq_kernel<<<dim3(CH_ROWS),256,0,stream>>>(BIGF, mrow, lrow, minl_stripe, pscale, PQ);
  pv(0);
}

extern "C" void kernel_launch(void* const* d_in, const int* in_sizes, int n_in,
                              void* d_out, int out_size, void* d_ws, size_t ws_size,
                              hipStream_t stream)
{
  (void)in_sizes; (void)n_in; (void)out_size; (void)ws_size;
  const float* targets = (const float*)d_in[0];
  const float* encoded = (const float*)d_in[1];
  const float* ln1_s = (const float*)d_in[4];
  const float* ln1_b = (const float*)d_in[5];
  const float* ln2_s = (const float*)d_in[6];
  const float* ln2_b = (const float*)d_in[7];
  const float* ln3_s = (const float*)d_in[8];
  const float* ln3_b = (const float*)d_in[9];
  const float* Wq_s = (const float*)d_in[10];
  const float* Wk_s = (const float*)d_in[11];
  const float* Wv_s = (const float*)d_in[12];
  const float* Wo_s = (const float*)d_in[13];
  const float* Wq_c = (const float*)d_in[14];
  const float* Wk_c = (const float*)d_in[15];
  const float* Wv_c = (const float*)d_in[16];
  const float* Wo_c = (const float*)d_in[17];
  const float* W1 = (const float*)d_in[18];
  const float* B1 = (const float*)d_in[19];
  const float* W2 = (const float*)d_in[20];
  const float* B2 = (const float*)d_in[21];
  float* OUT = (float*)d_out;

  char* ws = (char*)d_ws;
  const size_t MB = 1ull << 20;
  float* ACT_N = (float*)(ws +   0*MB);   // 16 MB  ln out; attn out
  float* ACT_Q = (float*)(ws +  16*MB);   // 16 MB
  float* ACT_K = (float*)(ws +  32*MB);   // 16 MB
  float* ACT_V = (float*)(ws +  48*MB);   // 16 MB
  float* BIGF  = (float*)(ws +  16*MB);   // 64 MB  logits chunk / mlp hidden (overlays Q/K/V)
  float* RES_X = (float*)(ws +  80*MB);   // 16 MB  x, then y (in-place)
  bf16*  XQ    = (bf16*) (ws +  96*MB);   // 32 MB  quantized act / P / h1
  bf16*  WQb   = (bf16*) (ws + 128*MB);   //  8 MB  quantized transposed weights
  bf16*  AQ    = (bf16*) (ws + 136*MB);   //  8 MB
  bf16*  KQ    = (bf16*) (ws + 144*MB);   //  8 MB
  bf16*  VQT   = (bf16*) (ws + 152*MB);   //  8 MB
  float* ST    = (float*)(ws + 160*MB);   //  1 MB  stripes + scales + row stats

  enum { XN=0, Q1=1, K1=2, V1=3, AO1=4, YN=5, Q2=6, K2=7, V2=8, AO2=9, ZN=10, H1S=11, ENC=12, P1=13, P2=14, MNL_C=17 };
  float* STR  = ST;                       // 18*1024 floats of stripes
  float* scl  = ST + 18432;               // 32 final scales
  float* wsc  = ST + 18496;               // 13312 per-column weight scales
  float* mrow = ST + 32768;
  float* lrow = ST + 98304;
#define STRIPE(s) (STR + (s)*1024)

  const long nAct = (long)NTOK * DIM;   // 4M elems

  init_kernel<<<dim3(128),256,0,stream>>>(ST);

  colamax_kernel<<<dim3( 4, 8),256,0,stream>>>(Wq_s, DIM, DIM, wsc +     0);
  colamax_kernel<<<dim3( 4, 8),256,0,stream>>>(Wk_s, DIM, DIM, wsc +  1024);
  colamax_kernel<<<dim3( 4, 8),256,0,stream>>>(Wv_s, DIM, DIM, wsc +  2048);
  colamax_kernel<<<dim3( 4, 8),256,0,stream>>>(Wo_s, DIM, DIM, wsc +  3072);
  colamax_kernel<<<dim3( 4, 8),256,0,stream>>>(Wq_c, DIM, DIM, wsc +  4096);
  colamax_kernel<<<dim3( 4, 8),256,0,stream>>>(Wk_c, DIM, DIM, wsc +  5120);
  colamax_kernel<<<dim3( 4, 8),256,0,stream>>>(Wv_c, DIM, DIM, wsc +  6144);
  colamax_kernel<<<dim3( 4, 8),256,0,stream>>>(Wo_c, DIM, DIM, wsc +  7168);
  colamax_kernel<<<dim3(16, 8),256,0,stream>>>(W1,   DIM, FF,  wsc +  8192);
  colamax_kernel<<<dim3( 4,32),256,0,stream>>>(W2,   FF,  DIM, wsc + 12288);
  finalize_kernel<<<dim3(52),256,0,stream>>>(wsc, 13312);

  // ================= self attention =================
  ln_kernel<<<dim3(NTOK),256,0,stream>>>(targets, ln1_s, ln1_b, ACT_N, STRIPE(XN));
  quant_kernel<<<dim3(4096),256,0,stream>>>(ACT_N, XQ, STRIPE(XN), &scl[XN], nAct);

  // fused QKV weights: wqT rows [0,1024)=Wq, [1024,2048)=Wk, [2048,3072)=Wv
  transq_kernel<<<dim3(32,32),dim3(32,8),0,stream>>>(Wq_s, WQb,             wsc +    0, DIM, DIM);
  transq_kernel<<<dim3(32,32),dim3(32,8),0,stream>>>(Wk_s, WQb + 1024*DIM,  wsc + 1024, DIM, DIM);
  transq_kernel<<<dim3(32,32),dim3(32,8),0,stream>>>(Wv_s, WQb + 2048*DIM,  wsc + 2048, DIM, DIM);
  gemm_kernel<64,128,64,0,false,false,false,true,true><<<dim3(48,32,1),256,0,stream>>>(
      XQ, WQb, ACT_Q, nullptr, &scl[XN], wsc + 0, 1, nullptr, 0.125f, STRIPE(Q1),
      NTOK, 3072, DIM, DIM, DIM, DIM, 0,0,0,0,0,0, nAct);

  quant_kernel<<<dim3(4096),256,0,stream>>>(ACT_Q, AQ, STRIPE(Q1), &scl[Q1], nAct);
  quant_kernel<<<dim3(4096),256,0,stream>>>(ACT_K, KQ, STRIPE(K1), &scl[K1], nAct);
  vtransq_kernel<<<dim3(8,128),dim3(64,8),0,stream>>>(ACT_V, VQT, STRIPE(V1), &scl[V1]);

  run_attention_self(AQ, KQ, VQT, BIGF, XQ, ACT_N,
                     &scl[Q1], &scl[K1], &scl[V1], &scl[P1], STRIPE(AO1), stream);

  quant_kernel<<<dim3(4096),256,0,stream>>>(ACT_N, XQ, STRIPE(AO1), &scl[AO1], nAct);
  transq_kernel<<<dim3(32,32),dim3(32,8),0,stream>>>(Wo_s, WQb, wsc + 3072, DIM, DIM);
  gemm_kernel<64,128,64,1,false,false,false,false,false><<<dim3(16,32,1),256,0,stream>>>(
      XQ, WQb, RES_X, targets, &scl[AO1], wsc + 3072, 1, nullptr, 1.0f, nullptr,
      NTOK, DIM, DIM, DIM, DIM, DIM, 0,0,0,0,0,0, 0);

  // ================= cross attention =================
  ln_kernel<<<dim3(NTOK),256,0,stream>>>(RES_X, ln2_s, ln2_b, ACT_N, STRIPE(YN));
  quant_kernel<<<dim3(4096),256,0,stream>>>(ACT_N, XQ, STRIPE(YN), &scl[YN], nAct);
  amax_kernel<<<dim3(2048),256,0,stream>>>(encoded, nAct, STRIPE(ENC));
  quant_kernel<<<dim3(4096),256,0,stream>>>(encoded, AQ, STRIPE(ENC), &scl[ENC], nAct);

  transq_kernel<<<dim3(32,32),dim3(32,8),0,stream>>>(Wq_c, WQb,            wsc + 4096, DIM, DIM);
  transq_kernel<<<dim3(32,32),dim3(32,8),0,stream>>>(Wk_c, WQb + 1024*DIM, wsc + 5120, DIM, DIM);
  transq_kernel<<<dim3(32,32),dim3(32,8),0,stream>>>(Wv_c, WQb + 2048*DIM, wsc + 6144, DIM, DIM);
  gemm_kernel<64,128,64,0,false,false,false,true,false><<<dim3(16,32,1),256,0,stream>>>(
      XQ, WQb, ACT_Q, nullptr, &scl[YN], wsc + 4096, 1, nullptr, 0.125f, STRIPE(Q2),
      NTOK, DIM, DIM, DIM, DIM, DIM, 0,0,0,0,0,0, 0);
  // fused KV (A = quantized encoded): chunks -> ACT_K, ACT_V
  gemm_kernel<64,128,64,0,false,false,false,true,true><<<dim3(32,32,1),256,0,stream>>>(
      AQ, WQb + 1024*DIM, ACT_K, nullptr, &scl[ENC], wsc + 5120, 1, nullptr, 1.0f, STRIPE(K2),
      NTOK, 2048, DIM, DIM, DIM, DIM, 0,0,0,0,0,0, nAct);

  quant_kernel<<<dim3(4096),256,0,stream>>>(ACT_Q, AQ, STRIPE(Q2), &scl[Q2], nAct);
  quant_kernel<<<dim3(4096),256,0,stream>>>(ACT_K, KQ, STRIPE(K2), &scl[K2], nAct);
  vtransq_kernel<<<dim3(8,128),dim3(64,8),0,stream>>>(ACT_V, VQT, STRIPE(V2), &scl[V2]);

  run_attention_cross(AQ, KQ, VQT, BIGF, XQ, ACT_N,
                      &scl[Q2], &scl[K2], &scl[V2], &scl[P2], STRIPE(MNL_C),
                      mrow, lrow, STRIPE(AO2), stream);

  quant_kernel<<<dim3(4096),256,0,stream>>>(ACT_N, XQ, STRIPE(AO2), &scl[AO2], nAct);
  transq_kernel<<<dim3(32,32),dim3(32,8),0,stream>>>(Wo_c, WQb, wsc + 7168, DIM, DIM);
  gemm_kernel<64,128,64,1,false,false,false,false,false><<<dim3(16,32,1),256,0,stream>>>(
      XQ, WQb, RES_X, RES_X, &scl[AO2], wsc + 7168, 1, nullptr, 1.0f, nullptr,
      NTOK, DIM, DIM, DIM, DIM, DIM, 0,0,0,0,0,0, 0);

  // ================= MLP =================
  ln_kernel<<<dim3(NTOK),256,0,stream>>>(RES_X, ln3_s, ln3_b, ACT_N, STRIPE(ZN));
  quant_kernel<<<dim3(4096),256,0,stream>>>(ACT_N, XQ, STRIPE(ZN), &scl[ZN], nAct);
  transq_kernel<<<dim3(128,32),dim3(32,8),0,stream>>>(W1, WQb, wsc + 8192, DIM, FF);
  gemm_kernel<64,128,64,0,false,true,true,true,false><<<dim3(64,32,1),256,0,stream>>>(
      XQ, WQb, BIGF, nullptr, &scl[ZN], wsc + 8192, 1, B1, 1.0f, STRIPE(H1S),
      NTOK, FF, DIM, DIM, DIM, FF, 0,0,0,0,0,0, 0);
  quant_kernel<<<dim3(8192),256,0,stream>>>(BIGF, XQ, STRIPE(H1S), &scl[H1S], (long)NTOK*FF);
  transq_kernel<<<dim3(32,128),dim3(32,8),0,stream>>>(W2, WQb, wsc + 12288, FF, DIM);
  gemm_kernel<64,128,64,1,false,false,true,false,false><<<dim3(16,32,1),256,0,stream>>>(
      XQ, WQb, OUT, RES_X, &scl[H1S], wsc + 12288, 1, B2, 1.0f, nullptr,
      NTOK, DIM, FF, FF, FF, DIM, 0,0,0,0,0,0, 0);
}